// Round 7
// baseline (305.069 us; speedup 1.0000x reference)
//
#include <hip/hip_runtime.h>
#include <hip/hip_bf16.h>
#include <math.h>

// Fused SelfAttention (attention over the HEADS axis, per token):
//   qkv = v @ [Wq|Wk|Wv]  (65536x256 @ 256x768, f16 MFMA)
//   per-token 8x8 softmax attention over heads (q in registers)
//   out = x @ Wp + bp       (65536x256 @ 256x256, f16 MFMA)
//
// MFMA orientation: D = A*B, A = W^T-tile (rows = output col n), B = v^T-tile
// (cols = tokens). C/D layout: col(lane&15)=token, row(quad*4+r)=n.
//
// R11: q-less LDS tile breaks the traffic/occupancy trade (7-round model:
// time = f(blocks/CU, L2 weight traffic); prefetch depth = dead lever).
// Wave w owns q-tiles {2w,2w+1} = head w's full q -> q never touches LDS;
// attention is re-assigned wave w = head w: q from registers (C-frag
// layout: lane(quad,l15) holds dims quad*4+r (+16) of token l15+16tt),
// k/vv from LDS, logits reduced across quads via shfl_xor(16/32), softmax
// in-lane, PV accumulates in C-frag layout, x -> dead k section.
// Row shrinks 776->520 f16 (k|vv only): TM=48 fits 3 blocks/CU
// (49,920 B x3 <= 160K) = R9's 0.70 GB weight traffic at R4's occupancy.
// Weight prefetch: depth-2 (wA/wB/wC), prologues hidden under prior phases.

#define DIMX      256
#define NH        8
#define HD        32
#define TM        48       // tokens per block
#define NTHREADS  512      // 8 waves
#define QS        520      // f16 units per row; 1040 B (16B-aligned)
#define KT        8        // 256/32 k-tiles
#define NT_QKV    48       // q: 0..15, k: 16..31, v: 32..47

typedef _Float16 f16x8 __attribute__((ext_vector_type(8)));
typedef _Float16 f16x4 __attribute__((ext_vector_type(4)));
typedef _Float16 f16x2 __attribute__((ext_vector_type(2)));
typedef float    f32x4 __attribute__((ext_vector_type(4)));

static __device__ __forceinline__ f16x2 pkrtz(float a, float b) {
    return (f16x2)__builtin_amdgcn_cvt_pkrtz(a, b);
}
static __device__ __forceinline__ f16x4 pk4(const f32x4& a) {
    f16x2 lo = pkrtz(a[0], a[1]), hi = pkrtz(a[2], a[3]);
    return (f16x4){ lo.x, lo.y, hi.x, hi.y };
}

// ---------------------------------------------------------------------------
// Prep: pack Wq|Wk|Wv and Wp into MFMA A-operand fragment order, fp32->f16.
// frag[j] = W[kt*32 + quad*8 + j][nt*16 + (lane&15)]
// packed index u = (nt*KT + kt)*64 + lane ; 8 f16 (16 B) per u, contiguous.
// ---------------------------------------------------------------------------
__global__ void pack_weights(const float* __restrict__ Wq,
                             const float* __restrict__ Wk,
                             const float* __restrict__ Wv,
                             const float* __restrict__ Wp,
                             _Float16* __restrict__ pk)
{
    const int QKV_FRAGS = NT_QKV * KT * 64;   // 24576
    int u = blockIdx.x * blockDim.x + threadIdx.x;  // 0..32767
    const float* W;
    int nt, kt, lane;
    if (u < QKV_FRAGS) {
        nt = u / (KT * 64); kt = (u / 64) % KT; lane = u % 64;
        if (nt < 16)      { W = Wq; }
        else if (nt < 32) { W = Wk; nt -= 16; }
        else              { W = Wv; nt -= 32; }
    } else {
        int u2 = u - QKV_FRAGS;
        nt = u2 / (KT * 64); kt = (u2 / 64) % KT; lane = u2 % 64;
        W = Wp;
    }
    const int n  = nt * 16 + (lane & 15);
    const int k0 = kt * 32 + (lane >> 4) * 8;
    f16x8 frag;
#pragma unroll
    for (int j = 0; j < 8; ++j)
        frag[j] = (_Float16)W[(size_t)(k0 + j) * DIMX + n];
    *(f16x8*)(pk + (size_t)u * 8) = frag;
}

// ---------------------------------------------------------------------------
// Main fused kernel. LDS: 48x520 f16 (49,920 B -> 3 blocks/CU).
//   sections: K cols [0,256) <- GEMM1 tiles 16..31 (k), immediate writeback;
//             VV cols [256,512) <- v input, later tiles 32..47 (vv, deferred);
//             x overwrites K section after attention. q never enters LDS.
// ---------------------------------------------------------------------------
__global__ __launch_bounds__(NTHREADS, 6)   // 6 waves/EU -> 3 blocks/CU
void fused_attn_mfma(const float* __restrict__ v,
                     const _Float16* __restrict__ Wqkv_pk,
                     const _Float16* __restrict__ Wp_pk,
                     const float* __restrict__ bp,
                     float* __restrict__ out,
                     int ntok)
{
    __shared__ __align__(16) _Float16 S[TM * QS];   // 49,920 B

    const int tid   = threadIdx.x;
    const int lane  = tid & 63;
    const int wv_id = tid >> 6;      // wave 0..7  (= head id in attention)
    const int l15   = lane & 15;
    const int quad  = lane >> 4;
    const int token0 = blockIdx.x * TM;
    int valid = ntok - token0; if (valid > TM) valid = TM;

    // GEMM1 tiles per wave: pass0 = {2 k-tiles, vA}; pass1 = {qA, qB, vB}.
    // k: immediate writeback to [0,256). v: deferred (aliases v input).
    // q: never written -- carried in registers into attention.
    const int tiles0[3] = { 16 + 2 * wv_id, 17 + 2 * wv_id, 32 + 2 * wv_id };
    const int tiles1[3] = { 2 * wv_id, 2 * wv_id + 1, 33 + 2 * wv_id };

    const f16x8* wb  = (const f16x8*)Wqkv_pk + lane;
    const f16x8* wb2 = (const f16x8*)Wp_pk + lane;

    // ---- stage 0: v-tile global loads (guarded) + pass0 weight prologue ----
    {
        const float4* src = (const float4*)(v + (size_t)token0 * DIMX);
        float4 t4[6];
#pragma unroll
        for (int i = 0; i < 6; ++i) {
            int u = tid + NTHREADS * i;       // 0..3071 float4 slots
            int m = u >> 6;
            t4[i] = (m < valid) ? src[u] : (float4){0.f, 0.f, 0.f, 0.f};
        }
#pragma unroll
        for (int i = 0; i < 6; ++i) {
            int u = tid + NTHREADS * i;
            int m = u >> 6;
            int c = (u & 63) * 4;
            f16x2 lo = pkrtz(t4[i].x, t4[i].y), hi = pkrtz(t4[i].z, t4[i].w);
            f16x4 b4 = { lo.x, lo.y, hi.x, hi.y };
            *(f16x4*)&S[m * QS + 256 + c] = b4;   // v input -> VV section
        }
    }
    f16x8 wA[3], wB[3];
#pragma unroll
    for (int j = 0; j < 3; ++j) wA[j] = wb[(size_t)(tiles0[j] * KT + 0) * 64];
#pragma unroll
    for (int j = 0; j < 3; ++j) wB[j] = wb[(size_t)(tiles0[j] * KT + 1) * 64];
    __syncthreads();   // b1: v tile visible in VV section

    // ---- GEMM1 pass0: {kA, kB, vA} x 3 tt ----------------------------------
    f32x4 acc0[3][3];
#pragma unroll
    for (int j = 0; j < 3; ++j)
#pragma unroll
        for (int tt = 0; tt < 3; ++tt)
            acc0[j][tt] = (f32x4){0.f, 0.f, 0.f, 0.f};

#pragma unroll
    for (int kt = 0; kt < KT; ++kt) {
        f16x8 wC[3];
        if (kt < KT - 2) {
#pragma unroll
            for (int j = 0; j < 3; ++j)
                wC[j] = wb[(size_t)(tiles0[j] * KT + kt + 2) * 64];
        } else {
#pragma unroll
            for (int j = 0; j < 3; ++j) wC[j] = wB[j];
        }
        f16x8 vf[3];
#pragma unroll
        for (int tt = 0; tt < 3; ++tt)
            vf[tt] = *(const f16x8*)&S[(tt * 16 + l15) * QS + 256 + kt * 32 + quad * 8];
#pragma unroll
        for (int j = 0; j < 3; ++j)
#pragma unroll
            for (int tt = 0; tt < 3; ++tt)
                acc0[j][tt] = __builtin_amdgcn_mfma_f32_16x16x32_f16(wA[j], vf[tt], acc0[j][tt], 0, 0, 0);
#pragma unroll
        for (int j = 0; j < 3; ++j) { wA[j] = wB[j]; wB[j] = wC[j]; }
    }

    // pass1 weight prologue (latency hides under pass0 writeback)
    f16x8 pA[3], pB[3];
#pragma unroll
    for (int j = 0; j < 3; ++j) pA[j] = wb[(size_t)(tiles1[j] * KT + 0) * 64];
#pragma unroll
    for (int j = 0; j < 3; ++j) pB[j] = wb[(size_t)(tiles1[j] * KT + 1) * 64];

    // k tiles: immediate writeback to K section [0,256); vA -> pending regs
    f16x4 pend0[3];
#pragma unroll
    for (int j = 0; j < 2; ++j)
#pragma unroll
        for (int tt = 0; tt < 3; ++tt)
            *(f16x4*)&S[(tt * 16 + l15) * QS + (tiles0[j] - 16) * 16 + quad * 4] = pk4(acc0[j][tt]);
#pragma unroll
    for (int tt = 0; tt < 3; ++tt) pend0[tt] = pk4(acc0[2][tt]);

    // ---- GEMM1 pass1: {qA, qB, vB} x 3 tt ----------------------------------
    f32x4 acc1[3][3];
#pragma unroll
    for (int j = 0; j < 3; ++j)
#pragma unroll
        for (int tt = 0; tt < 3; ++tt)
            acc1[j][tt] = (f32x4){0.f, 0.f, 0.f, 0.f};

#pragma unroll
    for (int kt = 0; kt < KT; ++kt) {
        f16x8 pC[3];
        if (kt < KT - 2) {
#pragma unroll
            for (int j = 0; j < 3; ++j)
                pC[j] = wb[(size_t)(tiles1[j] * KT + kt + 2) * 64];
        } else {
#pragma unroll
            for (int j = 0; j < 3; ++j) pC[j] = pB[j];
        }
        f16x8 vf[3];
#pragma unroll
        for (int tt = 0; tt < 3; ++tt)
            vf[tt] = *(const f16x8*)&S[(tt * 16 + l15) * QS + 256 + kt * 32 + quad * 8];
#pragma unroll
        for (int j = 0; j < 3; ++j)
#pragma unroll
            for (int tt = 0; tt < 3; ++tt)
                acc1[j][tt] = __builtin_amdgcn_mfma_f32_16x16x32_f16(pA[j], vf[tt], acc1[j][tt], 0, 0, 0);
#pragma unroll
        for (int j = 0; j < 3; ++j) { pA[j] = pB[j]; pB[j] = pC[j]; }
    }

    // q -> registers (f16, C-frag layout); vB -> pending
    f16x4 qf0[3], qf1[3], pend1[3];
#pragma unroll
    for (int tt = 0; tt < 3; ++tt) {
        qf0[tt]   = pk4(acc1[0][tt]);   // dims quad*4+r
        qf1[tt]   = pk4(acc1[1][tt]);   // dims 16+quad*4+r
        pend1[tt] = pk4(acc1[2][tt]);
    }

    // GEMM2 weight prologue (lead spans vv writeback + attention)
    const int nt0 = 2 * wv_id;
    f16x8 wA2[2], wB2[2];
#pragma unroll
    for (int j = 0; j < 2; ++j) wA2[j] = wb2[(size_t)((nt0 + j) * KT + 0) * 64];
#pragma unroll
    for (int j = 0; j < 2; ++j) wB2[j] = wb2[(size_t)((nt0 + j) * KT + 1) * 64];

    __syncthreads();   // b2: ALL v-input reads done; VV section writable

    // deferred vv writebacks: vA -> col 256+32w, vB -> col 256+32w+16
#pragma unroll
    for (int tt = 0; tt < 3; ++tt) {
        *(f16x4*)&S[(tt * 16 + l15) * QS + 256 + 32 * wv_id + quad * 4]      = pend0[tt];
        *(f16x4*)&S[(tt * 16 + l15) * QS + 256 + 32 * wv_id + 16 + quad * 4] = pend1[tt];
    }
    __syncthreads();   // b3: k|vv complete in LDS

    // ---- attention: wave w = head w; token t = tt*16+l15; quad = dim slice -
    // All 4 quads redundantly compute logits/softmax (each holds 8 of 32 dims,
    // reduced via shfl_xor 16/32); PV output stays in this lane's dim slice.
    f16x4 xq0[3], xq1[3];
    {
        const float scale = 0.17677669529663687f;  // 32^-0.5
#pragma unroll
        for (int tt = 0; tt < 3; ++tt) {
            const int t = tt * 16 + l15;
            const _Float16* krow = &S[t * QS];
            const _Float16* vrow = &S[t * QS + 256];

            float lg[NH];
#pragma unroll
            for (int g = 0; g < NH; ++g) {
                f16x4 ka = *(const f16x4*)&krow[g * HD + quad * 4];
                f16x4 kb = *(const f16x4*)&krow[g * HD + 16 + quad * 4];
                float p = 0.f;
#pragma unroll
                for (int r = 0; r < 4; ++r)
                    p += (float)qf0[tt][r] * (float)ka[r]
                       + (float)qf1[tt][r] * (float)kb[r];
                p += __shfl_xor(p, 16, 64);
                p += __shfl_xor(p, 32, 64);
                lg[g] = p * scale;
            }
            float mx = lg[0];
#pragma unroll
            for (int g = 1; g < NH; ++g) mx = fmaxf(mx, lg[g]);
            float se = 0.f;
#pragma unroll
            for (int g = 0; g < NH; ++g) { lg[g] = __expf(lg[g] - mx); se += lg[g]; }
            float inv = 1.f / se;

            float xr0[4] = {0.f, 0.f, 0.f, 0.f};
            float xr1[4] = {0.f, 0.f, 0.f, 0.f};
#pragma unroll
            for (int g = 0; g < NH; ++g) {
                f16x4 va = *(const f16x4*)&vrow[g * HD + quad * 4];
                f16x4 vb = *(const f16x4*)&vrow[g * HD + 16 + quad * 4];
                float w8 = lg[g] * inv;
#pragma unroll
                for (int r = 0; r < 4; ++r) {
                    xr0[r] += w8 * (float)va[r];
                    xr1[r] += w8 * (float)vb[r];
                }
            }
            f16x2 a0 = pkrtz(xr0[0], xr0[1]), b0 = pkrtz(xr0[2], xr0[3]);
            f16x2 a1 = pkrtz(xr1[0], xr1[1]), b1 = pkrtz(xr1[2], xr1[3]);
            xq0[tt] = (f16x4){ a0.x, a0.y, b0.x, b0.y };
            xq1[tt] = (f16x4){ a1.x, a1.y, b1.x, b1.y };
        }
    }
    __syncthreads();   // b4: all k reads done; K section writable (x tile)
#pragma unroll
    for (int tt = 0; tt < 3; ++tt) {
        const int t = tt * 16 + l15;
        *(f16x4*)&S[t * QS + 32 * wv_id + quad * 4]      = xq0[tt];
        *(f16x4*)&S[t * QS + 32 * wv_id + 16 + quad * 4] = xq1[tt];
    }
    __syncthreads();   // b5: x tile complete in [0,256)

    // ---- GEMM2: out = x @ Wp + bp; wave w owns n-tiles {2w, 2w+1} ----------
    {
        f32x4 acc2[2][3];
#pragma unroll
        for (int j = 0; j < 2; ++j)
#pragma unroll
            for (int tt = 0; tt < 3; ++tt)
                acc2[j][tt] = (f32x4){0.f, 0.f, 0.f, 0.f};

#pragma unroll
        for (int kt = 0; kt < KT; ++kt) {
            f16x8 wC2[2];
            if (kt < KT - 2) {
#pragma unroll
                for (int j = 0; j < 2; ++j)
                    wC2[j] = wb2[(size_t)((nt0 + j) * KT + kt + 2) * 64];
            } else {
#pragma unroll
                for (int j = 0; j < 2; ++j) wC2[j] = wB2[j];
            }
            f16x8 xf[3];
#pragma unroll
            for (int tt = 0; tt < 3; ++tt)
                xf[tt] = *(const f16x8*)&S[(tt * 16 + l15) * QS + kt * 32 + quad * 8];
#pragma unroll
            for (int j = 0; j < 2; ++j)
#pragma unroll
                for (int tt = 0; tt < 3; ++tt)
                    acc2[j][tt] = __builtin_amdgcn_mfma_f32_16x16x32_f16(wA2[j], xf[tt], acc2[j][tt], 0, 0, 0);
#pragma unroll
            for (int j = 0; j < 2; ++j) { wA2[j] = wB2[j]; wB2[j] = wC2[j]; }
        }

#pragma unroll
        for (int j = 0; j < 2; ++j) {
            f32x4 b = *(const f32x4*)&bp[(nt0 + j) * 16 + quad * 4];
#pragma unroll
            for (int tt = 0; tt < 3; ++tt) {
                int row = token0 + tt * 16 + l15;
                if (row < ntok) {
                    f32x4 o = acc2[j][tt] + b;
                    *(f32x4*)&out[(size_t)row * DIMX + (nt0 + j) * 16 + quad * 4] = o;
                }
            }
        }
    }
}

extern "C" void kernel_launch(void* const* d_in, const int* in_sizes, int n_in,
                              void* d_out, int out_size, void* d_ws, size_t ws_size,
                              hipStream_t stream) {
    const float* v  = (const float*)d_in[0];
    const float* Wq = (const float*)d_in[1];
    const float* Wk = (const float*)d_in[2];
    const float* Wv = (const float*)d_in[3];
    const float* Wp = (const float*)d_in[4];
    const float* bp = (const float*)d_in[5];
    float* out = (float*)d_out;

    _Float16* pk = (_Float16*)d_ws;                // 32768 frags * 16 B = 512 KB
    const _Float16* Wqkv_pk = pk;                  // 24576 frags
    const _Float16* Wp_pk   = pk + (size_t)24576 * 8;

    pack_weights<<<256, 128, 0, stream>>>(Wq, Wk, Wv, Wp, pk);

    const int ntokens = in_sizes[0] / DIMX;        // 65536
    const int nblk = (ntokens + TM - 1) / TM;      // 1366
    fused_attn_mfma<<<nblk, NTHREADS, 0, stream>>>(v, Wqkv_pk, Wp_pk, bp, out, ntokens);
}

// Round 8
// 194.335 us; speedup vs baseline: 1.5698x; 1.5698x over previous
//
#include <hip/hip_runtime.h>
#include <hip/hip_bf16.h>
#include <math.h>

// Fused SelfAttention (attention over the HEADS axis, per token):
//   qkv = v @ [Wq|Wk|Wv]  (65536x256 @ 256x768, f16 MFMA)
//   per-token 8x8 softmax attention over heads (q carried in registers)
//   out = x @ Wp + bp       (65536x256 @ 256x256, f16 MFMA)
//
// MFMA orientation: D = A*B, A = W^T-tile (rows = output col n), B = v^T-tile
// (cols = tokens). C/D layout: col(lane&15)=token, row(quad*4+r)=n.
//
// R12: q-less LDS tile at R4's exact occupancy/structure point, inside the
// 85-reg envelope (register-cap law, 7 configs: cap = 512/wavesPerEU combined
// V+A; (512,6) -> 85; R4 used 64; R11 died at ~130).
//  - TM=32, 3 blocks/CU, depth-1 weight prefetch (R4's proven 40V+24A shape).
//  - pass0 tiles {k,k,vA}, pass1 {qA,qB,vB}; q (= head w's full q, already in
//    C-frag layout) never touches LDS: 8 regs carried into attention.
//  - LDS row 776 -> 520 f16 (k|vv only, 33.3 KB/block): -33% footprint,
//    -20% LDS traffic, q round-trip deleted.
//  - attention: wave w = head w (R11-verified mapping): lane=(quad,l15,tt),
//    quad owns an 8-dim slice, logits reduced via shfl_xor(16/32), softmax
//    in-lane, PV in-slice; k/v bytes halved vs R4's redundant full-row reads.
//  - x -> dead K section; GEMM2 unchanged from R4.

#define DIMX      256
#define NH        8
#define HD        32
#define TM        32       // tokens per block
#define NTHREADS  512      // 8 waves
#define QS        520      // f16 units per row; 1040 B = 65 16B-slots (odd)
#define KT        8        // 256/32 k-tiles
#define NT_QKV    48       // q: 0..15, k: 16..31, v: 32..47

typedef _Float16 f16x8 __attribute__((ext_vector_type(8)));
typedef _Float16 f16x4 __attribute__((ext_vector_type(4)));
typedef _Float16 f16x2 __attribute__((ext_vector_type(2)));
typedef float    f32x4 __attribute__((ext_vector_type(4)));

static __device__ __forceinline__ f16x2 pkrtz(float a, float b) {
    return (f16x2)__builtin_amdgcn_cvt_pkrtz(a, b);
}
static __device__ __forceinline__ f16x4 pk4(const f32x4& a) {
    f16x2 lo = pkrtz(a[0], a[1]), hi = pkrtz(a[2], a[3]);
    return (f16x4){ lo.x, lo.y, hi.x, hi.y };
}

// ---------------------------------------------------------------------------
// Prep: pack Wq|Wk|Wv and Wp into MFMA A-operand fragment order, fp32->f16.
// frag[j] = W[kt*32 + quad*8 + j][nt*16 + (lane&15)]
// packed index u = (nt*KT + kt)*64 + lane ; 8 f16 (16 B) per u, contiguous.
// ---------------------------------------------------------------------------
__global__ void pack_weights(const float* __restrict__ Wq,
                             const float* __restrict__ Wk,
                             const float* __restrict__ Wv,
                             const float* __restrict__ Wp,
                             _Float16* __restrict__ pk)
{
    const int QKV_FRAGS = NT_QKV * KT * 64;   // 24576
    int u = blockIdx.x * blockDim.x + threadIdx.x;  // 0..32767
    const float* W;
    int nt, kt, lane;
    if (u < QKV_FRAGS) {
        nt = u / (KT * 64); kt = (u / 64) % KT; lane = u % 64;
        if (nt < 16)      { W = Wq; }
        else if (nt < 32) { W = Wk; nt -= 16; }
        else              { W = Wv; nt -= 32; }
    } else {
        int u2 = u - QKV_FRAGS;
        nt = u2 / (KT * 64); kt = (u2 / 64) % KT; lane = u2 % 64;
        W = Wp;
    }
    const int n  = nt * 16 + (lane & 15);
    const int k0 = kt * 32 + (lane >> 4) * 8;
    f16x8 frag;
#pragma unroll
    for (int j = 0; j < 8; ++j)
        frag[j] = (_Float16)W[(size_t)(k0 + j) * DIMX + n];
    *(f16x8*)(pk + (size_t)u * 8) = frag;
}

// ---------------------------------------------------------------------------
// Main fused kernel. LDS: 32x520 f16 (33,280 B -> 3 blocks/CU, LDS headroom).
//   K section cols [0,256): k tiles (immediate wb), later x tile.
//   VV section cols [256,512): v input, later vv tiles (deferred wb).
//   q never enters LDS.
// ---------------------------------------------------------------------------
__global__ __launch_bounds__(NTHREADS, 6)   // 6 waves/EU -> 3 blocks/CU, cap ~85 regs
void fused_attn_mfma(const float* __restrict__ v,
                     const _Float16* __restrict__ Wqkv_pk,
                     const _Float16* __restrict__ Wp_pk,
                     const float* __restrict__ bp,
                     float* __restrict__ out)
{
    __shared__ __align__(16) _Float16 S[TM * QS];   // 33,280 B

    const int tid   = threadIdx.x;
    const int lane  = tid & 63;
    const int wv_id = tid >> 6;      // wave 0..7  (= head id in attention)
    const int l15   = lane & 15;
    const int quad  = lane >> 4;
    const long token0 = (long)blockIdx.x * TM;

    // pass0 = {k(16+2w), k(17+2w), vA(32+2w)}; pass1 = {q(2w), q(2w+1), vB(33+2w)}
    const int tiles0[3] = { 16 + 2 * wv_id, 17 + 2 * wv_id, 32 + 2 * wv_id };
    const int tiles1[3] = { 2 * wv_id, 2 * wv_id + 1, 33 + 2 * wv_id };

    const f16x8* wb  = (const f16x8*)Wqkv_pk + lane;
    const f16x8* wb2 = (const f16x8*)Wp_pk + lane;

    // ---- stage 0: v tile fp32 -> f16 -> VV section [256,512) ---------------
    {
        const float4* src = (const float4*)(v + token0 * DIMX);
#pragma unroll
        for (int i = 0; i < 4; ++i) {
            int u = tid + NTHREADS * i;       // 0..2047 float4 slots
            int m = u >> 6;                   // token row (wave-uniform)
            int c = (u & 63) * 4;
            float4 t4 = src[u];
            f16x2 lo = pkrtz(t4.x, t4.y), hi = pkrtz(t4.z, t4.w);
            f16x4 b4 = { lo.x, lo.y, hi.x, hi.y };
            *(f16x4*)&S[m * QS + 256 + c] = b4;
        }
    }
    __syncthreads();   // b1: v tile visible in VV

    // ---- GEMM1 pass0: {k, k, vA} x 2 tt, depth-1 prefetch (R4 shape) -------
    f16x4 pend0[2];    // vA writeback pending (deferred past b2)
    {
        f32x4 acc0[2][3];
#pragma unroll
        for (int tt = 0; tt < 2; ++tt)
#pragma unroll
            for (int j = 0; j < 3; ++j)
                acc0[tt][j] = (f32x4){0.f, 0.f, 0.f, 0.f};

        f16x8 wcur[3];
#pragma unroll
        for (int j = 0; j < 3; ++j)
            wcur[j] = wb[(size_t)(tiles0[j] * KT) * 64];
        for (int kt = 0; kt < KT; ++kt) {
            const int ktn = (kt + 1 < KT) ? kt + 1 : KT - 1;
            f16x8 wnxt[3];
#pragma unroll
            for (int j = 0; j < 3; ++j)
                wnxt[j] = wb[(size_t)(tiles0[j] * KT + ktn) * 64];
            f16x8 vf[2];
#pragma unroll
            for (int tt = 0; tt < 2; ++tt)
                vf[tt] = *(const f16x8*)&S[(tt * 16 + l15) * QS + 256 + kt * 32 + quad * 8];
#pragma unroll
            for (int j = 0; j < 3; ++j) {
                acc0[0][j] = __builtin_amdgcn_mfma_f32_16x16x32_f16(wcur[j], vf[0], acc0[0][j], 0, 0, 0);
                acc0[1][j] = __builtin_amdgcn_mfma_f32_16x16x32_f16(wcur[j], vf[1], acc0[1][j], 0, 0, 0);
            }
#pragma unroll
            for (int j = 0; j < 3; ++j) wcur[j] = wnxt[j];
        }
        // k tiles: immediate writeback to K section (no alias with VV input)
#pragma unroll
        for (int tt = 0; tt < 2; ++tt)
#pragma unroll
            for (int j = 0; j < 2; ++j)
                *(f16x4*)&S[(tt * 16 + l15) * QS + (tiles0[j] - 16) * 16 + quad * 4] = pk4(acc0[tt][j]);
#pragma unroll
        for (int tt = 0; tt < 2; ++tt) pend0[tt] = pk4(acc0[tt][2]);
    }

    // ---- GEMM1 pass1: {qA, qB, vB} x 2 tt ----------------------------------
    f16x4 qf0[2], qf1[2], pend1[2];
    {
        f32x4 acc1[2][3];
#pragma unroll
        for (int tt = 0; tt < 2; ++tt)
#pragma unroll
            for (int j = 0; j < 3; ++j)
                acc1[tt][j] = (f32x4){0.f, 0.f, 0.f, 0.f};

        f16x8 wcur[3];
#pragma unroll
        for (int j = 0; j < 3; ++j)
            wcur[j] = wb[(size_t)(tiles1[j] * KT) * 64];
        for (int kt = 0; kt < KT; ++kt) {
            const int ktn = (kt + 1 < KT) ? kt + 1 : KT - 1;
            f16x8 wnxt[3];
#pragma unroll
            for (int j = 0; j < 3; ++j)
                wnxt[j] = wb[(size_t)(tiles1[j] * KT + ktn) * 64];
            f16x8 vf[2];
#pragma unroll
            for (int tt = 0; tt < 2; ++tt)
                vf[tt] = *(const f16x8*)&S[(tt * 16 + l15) * QS + 256 + kt * 32 + quad * 8];
#pragma unroll
            for (int j = 0; j < 3; ++j) {
                acc1[0][j] = __builtin_amdgcn_mfma_f32_16x16x32_f16(wcur[j], vf[0], acc1[0][j], 0, 0, 0);
                acc1[1][j] = __builtin_amdgcn_mfma_f32_16x16x32_f16(wcur[j], vf[1], acc1[1][j], 0, 0, 0);
            }
#pragma unroll
            for (int j = 0; j < 3; ++j) wcur[j] = wnxt[j];
        }
        // q -> registers (C-frag layout: lane holds dims quad*4+r / +16 of
        // head wv_id for token tt*16+l15); vB -> pending
#pragma unroll
        for (int tt = 0; tt < 2; ++tt) {
            qf0[tt]   = pk4(acc1[tt][0]);
            qf1[tt]   = pk4(acc1[tt][1]);
            pend1[tt] = pk4(acc1[tt][2]);
        }
    }
    __syncthreads();   // b2: ALL VV-input reads done; VV writable

    // deferred vv writebacks: vA -> VV col 256+32w, vB -> +16 (disjoint/wave)
#pragma unroll
    for (int tt = 0; tt < 2; ++tt) {
        *(f16x4*)&S[(tt * 16 + l15) * QS + 256 + 32 * wv_id + quad * 4]      = pend0[tt];
        *(f16x4*)&S[(tt * 16 + l15) * QS + 256 + 32 * wv_id + 16 + quad * 4] = pend1[tt];
    }
    __syncthreads();   // b3: k (K section) + vv (VV section) complete

    // ---- attention: wave w = head w; token t = tt*16+l15; quad = dim slice -
    // 4 quads redundantly compute logits (each dots its 8 of 32 dims, reduced
    // via shfl_xor 16/32); softmax in-lane; PV stays in this lane's dim slice.
    f16x4 xq0[2], xq1[2];
    {
        const float scale = 0.17677669529663687f;  // 32^-0.5
#pragma unroll
        for (int tt = 0; tt < 2; ++tt) {
            const int t = tt * 16 + l15;
            const _Float16* krow = &S[t * QS];
            const _Float16* vrow = &S[t * QS + 256];

            float lg[NH];
#pragma unroll
            for (int g = 0; g < NH; ++g) {
                f16x4 ka = *(const f16x4*)&krow[g * HD + quad * 4];
                f16x4 kb = *(const f16x4*)&krow[g * HD + 16 + quad * 4];
                float p = 0.f;
#pragma unroll
                for (int r = 0; r < 4; ++r)
                    p += (float)qf0[tt][r] * (float)ka[r]
                       + (float)qf1[tt][r] * (float)kb[r];
                p += __shfl_xor(p, 16, 64);
                p += __shfl_xor(p, 32, 64);
                lg[g] = p * scale;
            }
            float mx = lg[0];
#pragma unroll
            for (int g = 1; g < NH; ++g) mx = fmaxf(mx, lg[g]);
            float se = 0.f;
#pragma unroll
            for (int g = 0; g < NH; ++g) { lg[g] = __expf(lg[g] - mx); se += lg[g]; }
            float inv = 1.f / se;

            float xr0[4] = {0.f, 0.f, 0.f, 0.f};
            float xr1[4] = {0.f, 0.f, 0.f, 0.f};
#pragma unroll
            for (int g = 0; g < NH; ++g) {
                f16x4 va = *(const f16x4*)&vrow[g * HD + quad * 4];
                f16x4 vb = *(const f16x4*)&vrow[g * HD + 16 + quad * 4];
                float w8 = lg[g] * inv;
#pragma unroll
                for (int r = 0; r < 4; ++r) {
                    xr0[r] += w8 * (float)va[r];
                    xr1[r] += w8 * (float)vb[r];
                }
            }
            f16x2 a0 = pkrtz(xr0[0], xr0[1]), b0 = pkrtz(xr0[2], xr0[3]);
            f16x2 a1 = pkrtz(xr1[0], xr1[1]), b1 = pkrtz(xr1[2], xr1[3]);
            xq0[tt] = (f16x4){ a0.x, a0.y, b0.x, b0.y };
            xq1[tt] = (f16x4){ a1.x, a1.y, b1.x, b1.y };
        }
    }
    __syncthreads();   // b4: all k reads done; K section writable (x tile)
#pragma unroll
    for (int tt = 0; tt < 2; ++tt) {
        const int t = tt * 16 + l15;
        *(f16x4*)&S[t * QS + 32 * wv_id + quad * 4]      = xq0[tt];
        *(f16x4*)&S[t * QS + 32 * wv_id + 16 + quad * 4] = xq1[tt];
    }
    __syncthreads();   // b5: x tile complete in K section

    // ---- GEMM2: out = x @ Wp + bp; wave w owns n-tiles {2w, 2w+1} ----------
    {
        const int nt0 = wv_id * 2;
        f32x4 acc[2][2];
#pragma unroll
        for (int tt = 0; tt < 2; ++tt)
#pragma unroll
            for (int j = 0; j < 2; ++j)
                acc[tt][j] = (f32x4){0.f, 0.f, 0.f, 0.f};

        f16x8 wcur[2];
#pragma unroll
        for (int j = 0; j < 2; ++j)
            wcur[j] = wb2[(size_t)((nt0 + j) * KT) * 64];
        for (int kt = 0; kt < KT; ++kt) {
            const int ktn = (kt + 1 < KT) ? kt + 1 : KT - 1;
            f16x8 wnxt[2];
#pragma unroll
            for (int j = 0; j < 2; ++j)
                wnxt[j] = wb2[(size_t)((nt0 + j) * KT + ktn) * 64];
            f16x8 xf[2];
#pragma unroll
            for (int tt = 0; tt < 2; ++tt)
                xf[tt] = *(const f16x8*)&S[(tt * 16 + l15) * QS + kt * 32 + quad * 8];
#pragma unroll
            for (int j = 0; j < 2; ++j) {
                acc[0][j] = __builtin_amdgcn_mfma_f32_16x16x32_f16(wcur[j], xf[0], acc[0][j], 0, 0, 0);
                acc[1][j] = __builtin_amdgcn_mfma_f32_16x16x32_f16(wcur[j], xf[1], acc[1][j], 0, 0, 0);
            }
#pragma unroll
            for (int j = 0; j < 2; ++j) wcur[j] = wnxt[j];
        }
#pragma unroll
        for (int j = 0; j < 2; ++j) {
            f32x4 b = *(const f32x4*)&bp[(nt0 + j) * 16 + quad * 4];
#pragma unroll
            for (int tt = 0; tt < 2; ++tt) {
                f32x4 o = acc[tt][j] + b;
                *(f32x4*)&out[(token0 + tt * 16 + l15) * DIMX + (nt0 + j) * 16 + quad * 4] = o;
            }
        }
    }
}

extern "C" void kernel_launch(void* const* d_in, const int* in_sizes, int n_in,
                              void* d_out, int out_size, void* d_ws, size_t ws_size,
                              hipStream_t stream) {
    const float* v  = (const float*)d_in[0];
    const float* Wq = (const float*)d_in[1];
    const float* Wk = (const float*)d_in[2];
    const float* Wv = (const float*)d_in[3];
    const float* Wp = (const float*)d_in[4];
    const float* bp = (const float*)d_in[5];
    float* out = (float*)d_out;

    _Float16* pk = (_Float16*)d_ws;                // 32768 frags * 16 B = 512 KB
    const _Float16* Wqkv_pk = pk;                  // 24576 frags
    const _Float16* Wp_pk   = pk + (size_t)24576 * 8;

    pack_weights<<<256, 128, 0, stream>>>(Wq, Wk, Wv, Wp, pk);

    const int ntokens = in_sizes[0] / DIMX;        // 65536
    fused_attn_mfma<<<ntokens / TM, NTHREADS, 0, stream>>>(v, Wqkv_pk, Wp_pk, bp, out);
}